// Round 4
// baseline (148.498 us; speedup 1.0000x reference)
//
#include <hip/hip_runtime.h>
#include <hip/hip_bf16.h>

// Problem constants (from reference)
#define BB 1024
#define SS 200
#define PQ_M 8
#define VALS 256
#define SUB_DIM 16
#define N_TOKENS (BB * SS)             // 204800
#define OUT_PER_TOKEN (PQ_M * SUB_DIM) // 128 floats = 512 B

#define T_PER_THREAD 8
#define TOK_SLICE (N_TOKENS / T_PER_THREAD)  // 25600

// clang native vector type — required by __builtin_nontemporal_{load,store}
typedef __attribute__((ext_vector_type(4))) float v4f;

// 32 threads per token-slot; each thread services 8 tokens (slot + j*25600)
// with fully independent load chains (8x memory-level parallelism per lane).
// Within each token: thread t writes float4 #t of the token's 512B output;
// m = t>>2 selects the PQ dim, t&3 the 16B sub-chunk. Stores are
// nontemporal (105MB stream, no reuse) and perfectly coalesced: wave64 =
// 2 consecutive tokens = contiguous 1KB per store instruction.
__global__ __launch_bounds__(256) void pq_gather_kernel(
    const int*   __restrict__ ids,      // [N_TOKENS] item ids (int32)
    const int*   __restrict__ codes,    // [(NUM_ITEMS+2) * PQ_M] byte codes
    const float* __restrict__ cent,     // [PQ_M * VALS * SUB_DIM] fp32
    float*       __restrict__ out)      // [N_TOKENS * 128] fp32
{
    const int gid  = blockIdx.x * blockDim.x + threadIdx.x;
    const int t    = gid & 31;          // 0..31 within token
    const int slot = gid >> 5;          // 0..TOK_SLICE-1
    const int m    = t >> 2;            // PQ dim 0..7
    const int c4   = t & 3;             // float4 chunk within sub-vector

    // Stage 1: 8 independent id loads (one vmcnt batch)
    int id[T_PER_THREAD];
#pragma unroll
    for (int j = 0; j < T_PER_THREAD; ++j)
        id[j] = __builtin_nontemporal_load(ids + slot + j * TOK_SLICE);

    // Stage 2: 8 independent random code gathers (single-touch 32MB table)
    int code[T_PER_THREAD];
#pragma unroll
    for (int j = 0; j < T_PER_THREAD; ++j)
        code[j] = __builtin_nontemporal_load(codes + id[j] * PQ_M + m);

    // Stage 3: 8 independent centroid v4f reads (L2-resident 128KB table)
    v4f v[T_PER_THREAD];
    const v4f* cent4 = (const v4f*)cent;
#pragma unroll
    for (int j = 0; j < T_PER_THREAD; ++j)
        v[j] = cent4[(m * VALS + code[j]) * (SUB_DIM / 4) + c4];

    // Stage 4: 8 coalesced nontemporal v4f stores
#pragma unroll
    for (int j = 0; j < T_PER_THREAD; ++j) {
        v4f* dst = (v4f*)(out + (size_t)(slot + j * TOK_SLICE) * OUT_PER_TOKEN) + t;
        __builtin_nontemporal_store(v[j], dst);
    }
}

extern "C" void kernel_launch(void* const* d_in, const int* in_sizes, int n_in,
                              void* d_out, int out_size, void* d_ws, size_t ws_size,
                              hipStream_t stream)
{
    const int*   ids   = (const int*)d_in[0];    // input_ids [1024,200]
    const int*   codes = (const int*)d_in[1];    // item_codes [1000002,8]
    const float* cent  = (const float*)d_in[2];  // centroids [8,256,16] fp32
    float*       out   = (float*)d_out;          // [1024,200,128] fp32

    const int total_threads = TOK_SLICE * 32;    // 819,200
    const int block = 256;
    const int grid  = total_threads / block;     // 3200
    pq_gather_kernel<<<grid, block, 0, stream>>>(ids, codes, cent, out);
}